// Round 10
// baseline (61.996 us; speedup 1.0000x reference)
//
#include <hip/hip_runtime.h>

// ZBL repulsion energy: out[b] = sum_{n,k} KEHALF * f(a*d) * Zi*Zj*mask / d
// B=16, N=8192, K=128 in the bench (shapes derived from in_sizes).
//
// Round-10 = R8's depth ring + R5's LUT, combined without the occupancy loss:
//  - ring DEPTH 4->2 (12KB): per-wave iter wall ~3000cy >> 900cy HBM latency,
//    so depth-2 covers it; frees 12KB of LDS.
//  - f(ad) LUT in LDS: 1024 x {f, df} as TWO b32 arrays (all 32 banks).
//    Replaces 4 exp2 + 4 fma + 3 add per edge (trans-pipe heavy, VALU=37%)
//    with 2 random b32 gathers + ~6 VALU.
//  - LDS/block = 12288 ring + N*2 tab + 8192 LUT = 36864 -> 4 blocks/CU,
//    32 waves/CU, same grid (64,16).

#define KEHALF_F 7.199822675975274f
#define LOG2E_F  1.4426950408889634f
#define DEPTH    2
#define GRAN     64       // edges per wave-iteration
#define WPB      8        // waves per block (512 threads)
#define SLOTB    768      // 256B idx + 256B mask + 256B dist
#define LUTN     1024
#define LUT_ADMAX 80.0f

__device__ __forceinline__ float softplus_f(float x) {
    return (x > 20.f) ? x : log1pf(__expf(x));
}

// ---------------- precompute: scalars + packed u16 per-atom table ----------------
// scal: [5..8]=e_i [9]=qb [10]=qs [11..14]=log2(w_i) (exp2 path for fallback)
__global__ void zbl_pre(const int* __restrict__ zn,
                        const float* __restrict__ adiv,
                        const float* __restrict__ apow,
                        const float* __restrict__ c1, const float* __restrict__ c2,
                        const float* __restrict__ c3, const float* __restrict__ c4,
                        const float* __restrict__ a1, const float* __restrict__ a2,
                        const float* __restrict__ a3, const float* __restrict__ a4,
                        unsigned short* __restrict__ packed, float* __restrict__ scal,
                        int total_atoms)
{
    int i = blockIdx.x * blockDim.x + threadIdx.x;
    const float spa = softplus_f(apow[0]);
    const float sad = softplus_f(adiv[0]);
    const float qb  = sad;                                  // Z=1 -> zps=sad
    const float qmax = sad * __expf(spa * __logf(94.f));
    const float qs  = (qmax - qb) * (1.f / 511.f);
    if (i == 0) {
        float s1 = softplus_f(c1[0]), s2 = softplus_f(c2[0]);
        float s3 = softplus_f(c3[0]), s4 = softplus_f(c4[0]);
        float inv = KEHALF_F / (s1 + s2 + s3 + s4);         // fold KEHALF
        float w1 = s1 * inv, w2 = s2 * inv, w3 = s3 * inv, w4 = s4 * inv;
        scal[0] = sad;
        scal[1] = w1; scal[2] = w2; scal[3] = w3; scal[4] = w4;
        scal[5] = -softplus_f(a1[0]) * LOG2E_F;
        scal[6] = -softplus_f(a2[0]) * LOG2E_F;
        scal[7] = -softplus_f(a3[0]) * LOG2E_F;
        scal[8] = -softplus_f(a4[0]) * LOG2E_F;
        scal[9]  = qb;
        scal[10] = qs;
        scal[11] = __log2f(w1);
        scal[12] = __log2f(w2);
        scal[13] = __log2f(w3);
        scal[14] = __log2f(w4);
    }
    if (i < total_atoms) {
        unsigned int Z = (unsigned int)zn[i];
        float Zf = (float)Z;
        float zps = sad * __expf(spa * __logf(Zf));         // sp(adiv) * Z^sp(apow)
        float qf = (zps - qb) / qs;
        int q = (int)(qf + 0.5f);
        if (q < 0) q = 0;
        if (q > 511) q = 511;
        packed[i] = (unsigned short)(((unsigned)q << 7) | (Z & 0x7Fu));
    }
}

// ---------------- LUT builder: f(x) = KEHALF_norm * sum w_i exp(-s_i x) ----------------
// lut layout in ws: [LUTN floats f][LUTN floats df]  (contiguous 8KB)
__global__ void zbl_lut_k(const float* __restrict__ c1, const float* __restrict__ c2,
                          const float* __restrict__ c3, const float* __restrict__ c4,
                          const float* __restrict__ a1, const float* __restrict__ a2,
                          const float* __restrict__ a3, const float* __restrict__ a4,
                          float* __restrict__ lut)
{
    int i = blockIdx.x * blockDim.x + threadIdx.x;
    if (i >= LUTN) return;
    float s1 = softplus_f(c1[0]), s2 = softplus_f(c2[0]);
    float s3 = softplus_f(c3[0]), s4 = softplus_f(c4[0]);
    float inv = KEHALF_F / (s1 + s2 + s3 + s4);
    float w1 = s1 * inv, w2 = s2 * inv, w3 = s3 * inv, w4 = s4 * inv;
    float g1 = -softplus_f(a1[0]), g2 = -softplus_f(a2[0]);
    float g3 = -softplus_f(a3[0]), g4 = -softplus_f(a4[0]);
    const float h = LUT_ADMAX / (float)(LUTN - 1);
    float x0 = (float)i * h, x1 = x0 + h;
    float f0 = w1 * __expf(g1 * x0) + w2 * __expf(g2 * x0)
             + w3 * __expf(g3 * x0) + w4 * __expf(g4 * x0);
    float f1 = w1 * __expf(g1 * x1) + w2 * __expf(g2 * x1)
             + w3 * __expf(g3 * x1) + w4 * __expf(g4 * x1);
    lut[i] = f0;
    lut[LUTN + i] = f1 - f0;
}

// ---------------- main: depth-2 async ring + LDS tab + LDS LUT ----------------
extern __shared__ char smem[];   // [N*2 B tab][4KB lutF][4KB lutD]

// one width-16 global_load_lds stages the whole 768B slot:
// lanes 0-15 -> idx bytes [0,256), 16-31 -> mask [256,512), 32-47 -> dist [512,768)
#define STAGE1(slotp, it) do {                                                    \
    const char* _g = (lane < 16) ? (const char*)(nb_ + ((it) << 6))               \
                   : (lane < 32) ? (const char*)(mk_ + ((it) << 6))               \
                                 : (const char*)(ds_ + ((it) << 6));              \
    _g += (lane & 15) * 16;                                                       \
    if (lane < 48)                                                                \
        __builtin_amdgcn_global_load_lds(                                         \
            (const __attribute__((address_space(1))) void*)_g,                    \
            (__attribute__((address_space(3))) void*)(slotp), 16, 0, 0);          \
} while (0)

#define CONSUME(sp, it) do {                                                      \
    const int   ji = *(const int*)  ((sp) + (lane << 2));                         \
    const float mm = *(const float*)((sp) + 256 + (lane << 2));                   \
    const float dd = *(const float*)((sp) + 512 + (lane << 2));                   \
    const int r = rw + ((it) << 6) + lane;                                        \
    const unsigned int wi_ = tab[r >> kshift];                                    \
    const unsigned int wj_ = tab[ji];                                             \
    const float zpi = fmaf((float)(wi_ >> 7), qs, qb);                            \
    const float Zi  = (float)(wi_ & 0x7Fu);                                       \
    const float zpj = fmaf((float)(wj_ >> 7), qs, qb);                            \
    const float Zj  = (float)(wj_ & 0x7Fu);                                       \
    const float zz = Zi * Zj * mm;                                                \
    const float ad = (zpi + zpj) * (mm * dd);                                     \
    float t = fminf(ad * lscale, 1023.0f);                                        \
    const int   li = (int)t;                                                      \
    const float fr = t - (float)li;                                               \
    const float f  = fmaf(fr, lutD[li], lutF[li]);                                \
    acc += f * zz * __builtin_amdgcn_rcpf(dd);                                    \
} while (0)

__global__ __launch_bounds__(512, 8) void zbl_main10(
        const int*            __restrict__ neighbors,
        const float*          __restrict__ mask,
        const float*          __restrict__ dist,
        const unsigned short* __restrict__ packed,
        const float*          __restrict__ lutg,
        const float*          __restrict__ scal,
        float*                __restrict__ out,
        int N, int kshift, int epb, int iters)
{
    __shared__ char stage[WPB][DEPTH][SLOTB];   // 12288 B static

    unsigned short* tab  = (unsigned short*)smem;
    float*          lutF = (float*)(smem + (size_t)N * 2);
    float*          lutD = lutF + LUTN;

    const int tid  = threadIdx.x;
    const int w    = tid >> 6;
    const int lane = tid & 63;
    const int b    = blockIdx.y;

    // wave's contiguous edge span within batch b
    const int rw = (blockIdx.x * WPB + w) * (iters * GRAN);
    const size_t ebase = (size_t)b * epb + (size_t)rw;
    const int*   nb_ = neighbors + ebase;
    const float* mk_ = mask      + ebase;
    const float* ds_ = dist      + ebase;

    // 1) tab + LUT global loads first (oldest in vmem queue)
    const uint4* s4 = (const uint4*)(packed + (size_t)b * N);
    const uint4* l4 = (const uint4*)lutg;               // 512 uint4 = 8KB
    const int n8 = N >> 3;                              // # tab uint4 (<=1024)
    uint4 tv0, tv1, tv2;
    const bool h0 = (tid < n8);
    const bool h1 = (tid + 512 < n8);
    if (h0) tv0 = s4[tid];
    if (h1) tv1 = s4[tid + 512];
    tv2 = l4[tid];                                      // tid < 512 always

    // 2) ring prologue: issue DEPTH slots (1 instr each)
    {
        char* sp0 = &stage[w][0][0]; STAGE1(sp0, 0);
        char* sp1 = &stage[w][1][0]; STAGE1(sp1, 1);
    }

    // 3) write tab + LUT to LDS (waits only the older tab/LUT vmem loads)
    {
        uint4* t4 = (uint4*)tab;
        if (h0) t4[tid] = tv0;
        if (h1) t4[tid + 512] = tv1;
        uint4* u4 = (uint4*)lutF;
        u4[tid] = tv2;
    }
    const float qb = scal[9], qs = scal[10];
    const float lscale = (float)(LUTN - 1) * (1.0f / LUT_ADMAX);
    __syncthreads();

    float acc = 0.f;
    int it = 0;

    // main loop: steady-state counted wait, restage same slot, no barriers
    for (; it < iters - DEPTH; ++it) {
        asm volatile("s_waitcnt vmcnt(1)" ::: "memory");
        char* sp = &stage[w][it & (DEPTH - 1)][0];
        const int   ji = *(const int*)  (sp + (lane << 2));
        const float mm = *(const float*)(sp + 256 + (lane << 2));
        const float dd = *(const float*)(sp + 512 + (lane << 2));
        asm volatile("s_waitcnt lgkmcnt(0)" ::: "memory");   // slot consumed
        STAGE1(sp, it + DEPTH);
        const int r = rw + (it << 6) + lane;
        const unsigned int wi_ = tab[r >> kshift];
        const unsigned int wj_ = tab[ji];
        const float zpi = fmaf((float)(wi_ >> 7), qs, qb);
        const float Zi  = (float)(wi_ & 0x7Fu);
        const float zpj = fmaf((float)(wj_ >> 7), qs, qb);
        const float Zj  = (float)(wj_ & 0x7Fu);
        const float zz = Zi * Zj * mm;
        const float ad = (zpi + zpj) * (mm * dd);
        float t = fminf(ad * lscale, 1023.0f);
        const int   li = (int)t;
        const float fr = t - (float)li;
        const float f  = fmaf(fr, lutD[li], lutF[li]);
        acc += f * zz * __builtin_amdgcn_rcpf(dd);
    }

    // epilogue: 2 iterations with tightening waits (1/0), no restage
    {
        asm volatile("s_waitcnt vmcnt(1)" ::: "memory");
        char* sp = &stage[w][it & (DEPTH - 1)][0];
        CONSUME(sp, it); ++it;
    }
    {
        asm volatile("s_waitcnt vmcnt(0)" ::: "memory");
        char* sp = &stage[w][it & (DEPTH - 1)][0];
        CONSUME(sp, it); ++it;
    }

    // reduce: wave shuffle, then cross-wave via reused stage LDS, one atomic
    #pragma unroll
    for (int off = 32; off > 0; off >>= 1) acc += __shfl_down(acc, off);
    __syncthreads();                        // all waves past vmcnt(0)
    float* wred = (float*)&stage[0][0][0];  // reuse (all ring traffic done)
    if (lane == 0) wred[w] = acc;
    __syncthreads();
    if (tid == 0) {
        float t = 0.f;
        #pragma unroll
        for (int i = 0; i < WPB; ++i) t += wred[i];
        atomicAdd(&out[b], t);
    }
}

// ---------------- fallback (generic shapes, not used in bench) ----------------
__global__ void zbl_fallback(const int* __restrict__ neighbors,
                             const float* __restrict__ mask,
                             const float* __restrict__ dist,
                             const unsigned short* __restrict__ packed,
                             const float* __restrict__ scal,
                             float* __restrict__ out,
                             int N, int K, int epb, int total_edges)
{
    const int e = blockIdx.x * blockDim.x + threadIdx.x;
    if (e >= total_edges) return;
    const float e1 = scal[5], e2 = scal[6], e3 = scal[7], e4 = scal[8];
    const float qb = scal[9], qs = scal[10];
    const float l1 = scal[11], l2 = scal[12], l3 = scal[13], l4 = scal[14];
    const int b = e / epb;
    const int n = (e - b * epb) / K;
    const unsigned int wi = packed[(size_t)b * N + n];
    const unsigned int wj = packed[(size_t)b * N + neighbors[e]];
    const float zpi = fmaf((float)(wi >> 7), qs, qb);
    const float zpj = fmaf((float)(wj >> 7), qs, qb);
    const float Zi = (float)(wi & 0x7Fu), Zj = (float)(wj & 0x7Fu);
    const float m = mask[e], d = dist[e];
    const float ad = (zpi + zpj) * (m * d);
    const float f = exp2f(fmaf(e1, ad, l1)) + exp2f(fmaf(e2, ad, l2))
                  + exp2f(fmaf(e3, ad, l3)) + exp2f(fmaf(e4, ad, l4));
    const float corr = (m != 0.f) ? (f * Zi * Zj * m / d) : 0.f;
    if (corr != 0.f) atomicAdd(&out[b], corr);
}

extern "C" void kernel_launch(void* const* d_in, const int* in_sizes, int n_in,
                              void* d_out, int out_size, void* d_ws, size_t ws_size,
                              hipStream_t stream) {
    const int*   neighbors = (const int*)  d_in[0];
    const float* nb_mask   = (const float*)d_in[1];
    const int*   zn        = (const int*)  d_in[2];
    const float* dist      = (const float*)d_in[3];
    const float* adiv = (const float*)d_in[4];
    const float* apow = (const float*)d_in[5];
    const float* c1 = (const float*)d_in[6];
    const float* c2 = (const float*)d_in[7];
    const float* c3 = (const float*)d_in[8];
    const float* c4 = (const float*)d_in[9];
    const float* a1 = (const float*)d_in[10];
    const float* a2 = (const float*)d_in[11];
    const float* a3 = (const float*)d_in[12];
    const float* a4 = (const float*)d_in[13];

    const int total_edges = in_sizes[0];   // B*N*K
    const int total_atoms = in_sizes[2];   // B*N
    const int B = out_size;                // [B,1] fp32 output
    const int N = total_atoms / B;
    const int K = total_edges / total_atoms;
    const int epb = N * K;

    float*          scal   = (float*)d_ws;                         // 15 f32
    unsigned short* packed = (unsigned short*)((char*)d_ws + 64);  // B*N u16
    const size_t lut_off = (64 + (size_t)total_atoms * 2 + 15) & ~(size_t)15;
    float*          lutg   = (float*)((char*)d_ws + lut_off);      // 2*LUTN f32

    hipMemsetAsync(d_out, 0, (size_t)out_size * sizeof(float), stream);

    {
        const int threads = 256;
        const int blocks = (total_atoms + threads - 1) / threads;
        zbl_pre<<<blocks, threads, 0, stream>>>(zn, adiv, apow, c1, c2, c3, c4,
                                                a1, a2, a3, a4,
                                                packed, scal, total_atoms);
    }
    zbl_lut_k<<<LUTN / 256, 256, 0, stream>>>(c1, c2, c3, c4, a1, a2, a3, a4, lutg);

    int kshift = 0;
    while ((1 << kshift) < K && kshift < 30) kshift++;
    const bool kpow2 = ((1 << kshift) == K);

    // fast path: iters=32 per wave, 8 waves/block, granule 64
    const int ITERS = 32;
    const int span_block = WPB * GRAN * ITERS;          // 16384 edges/block
    const size_t lds_dyn = (size_t)N * 2 + (size_t)2 * LUTN * 4;
    const bool fast = kpow2 && (N % 8 == 0) && (N <= 8192) &&
                      (epb % span_block == 0) &&
                      (lut_off + 2 * LUTN * 4 <= ws_size);
    if (fast) {
        const int bpb = epb / span_block;               // blocks per batch
        dim3 grid(bpb, B);
        zbl_main10<<<grid, 512, lds_dyn, stream>>>(
            neighbors, nb_mask, dist, packed, lutg, scal, (float*)d_out,
            N, kshift, epb, ITERS);
    } else {
        const int threads = 256;
        const int blocks = (total_edges + threads - 1) / threads;
        zbl_fallback<<<blocks, threads, 0, stream>>>(
            neighbors, nb_mask, dist, packed, scal, (float*)d_out,
            N, K, epb, total_edges);
    }
}

// Round 11
// 56.086 us; speedup vs baseline: 1.1054x; 1.1054x over previous
//
#include <hip/hip_runtime.h>

// ZBL repulsion energy: out[b] = sum_{n,k} KEHALF * f(a*d) * Zi*Zj*mask / d
// B=16, N=8192, K=128 in the bench (shapes derived from in_sizes).
//
// Round-11 = R8's ring (best so far) + 2 edges/lane/iteration (GRAN=128):
//  - slot = 1536B ([512 idx][512 mask][512 dist]) staged by TWO full-width
//    global_load_lds (instr A: lanes 0-31 idx, 32-63 mask; instr B: lanes
//    0-31 dist). Full 64-lane utilization (R8 used 48/64).
//  - slot reads: 3x ds_read_b64 per lane (pair of edges) — same instr count
//    as R8 for 2x the edges; row atom tab[r>>k] read+decoded once per pair.
//  - compute = two independent chains -> ILP fills the latency gaps that
//    made R8's pipes additive (R8-R10 post-mortem: no pipe >40% busy).
//  - DEPTH=2: LDS = 8*2*1536 + 16384 = 40960 B exactly -> 4 blocks/CU,
//    32 waves/CU; steady vmcnt(2) (2 instrs/slot), epilogue 2/0.

#define KEHALF_F 7.199822675975274f
#define LOG2E_F  1.4426950408889634f
#define DEPTH    2
#define GRAN     128      // edges per wave-iteration (2 per lane)
#define WPB      8        // waves per block (512 threads)
#define SLOTB    1536     // 512B idx + 512B mask + 512B dist
#define ITERS    16

__device__ __forceinline__ float softplus_f(float x) {
    return (x > 20.f) ? x : log1pf(__expf(x));
}

// ---------------- precompute: scalars + packed u16 per-atom table ----------------
// scal: [5..8]=e_i(=-sp(a_i)*log2e) [9]=qb [10]=qs [11..14]=log2(w_i*KEHALF)
__global__ void zbl_pre(const int* __restrict__ zn,
                        const float* __restrict__ adiv,
                        const float* __restrict__ apow,
                        const float* __restrict__ c1, const float* __restrict__ c2,
                        const float* __restrict__ c3, const float* __restrict__ c4,
                        const float* __restrict__ a1, const float* __restrict__ a2,
                        const float* __restrict__ a3, const float* __restrict__ a4,
                        unsigned short* __restrict__ packed, float* __restrict__ scal,
                        int total_atoms)
{
    int i = blockIdx.x * blockDim.x + threadIdx.x;
    const float spa = softplus_f(apow[0]);
    const float sad = softplus_f(adiv[0]);
    const float qb  = sad;                                  // Z=1 -> zps=sad
    const float qmax = sad * __expf(spa * __logf(94.f));
    const float qs  = (qmax - qb) * (1.f / 511.f);
    if (i == 0) {
        float s1 = softplus_f(c1[0]), s2 = softplus_f(c2[0]);
        float s3 = softplus_f(c3[0]), s4 = softplus_f(c4[0]);
        float inv = KEHALF_F / (s1 + s2 + s3 + s4);         // fold KEHALF
        float w1 = s1 * inv, w2 = s2 * inv, w3 = s3 * inv, w4 = s4 * inv;
        scal[0] = sad;
        scal[1] = w1; scal[2] = w2; scal[3] = w3; scal[4] = w4;
        scal[5] = -softplus_f(a1[0]) * LOG2E_F;             // exp2 exponents
        scal[6] = -softplus_f(a2[0]) * LOG2E_F;
        scal[7] = -softplus_f(a3[0]) * LOG2E_F;
        scal[8] = -softplus_f(a4[0]) * LOG2E_F;
        scal[9]  = qb;
        scal[10] = qs;
        scal[11] = __log2f(w1);                             // weight -> exponent
        scal[12] = __log2f(w2);
        scal[13] = __log2f(w3);
        scal[14] = __log2f(w4);
    }
    if (i < total_atoms) {
        unsigned int Z = (unsigned int)zn[i];
        float Zf = (float)Z;
        float zps = sad * __expf(spa * __logf(Zf));         // sp(adiv) * Z^sp(apow)
        float qf = (zps - qb) / qs;
        int q = (int)(qf + 0.5f);
        if (q < 0) q = 0;
        if (q > 511) q = 511;
        packed[i] = (unsigned short)(((unsigned)q << 7) | (Z & 0x7Fu));
    }
}

// ---------------- main: depth-2 ring, 2 edges/lane, 32 waves/CU ----------------
extern __shared__ unsigned short tab[];   // N u16 (dynamic, after static)

// two full-width global_load_lds stage the 1536B slot:
// instr A: lanes 0-31 -> idx [0,512), lanes 32-63 -> mask [512,1024)
// instr B: lanes 0-31 -> dist [1024,1536)
#define STAGE2(slotp, it) do {                                                    \
    const char* _gA = (lane < 32)                                                 \
        ? (const char*)(nb_ + ((it) << 7))                                        \
        : (const char*)(mk_ + ((it) << 7)) - 512;                                 \
    _gA += lane * 16;                                                             \
    __builtin_amdgcn_global_load_lds(                                             \
        (const __attribute__((address_space(1))) void*)_gA,                       \
        (__attribute__((address_space(3))) void*)(slotp), 16, 0, 0);              \
    if (lane < 32) {                                                              \
        const char* _gB = (const char*)(ds_ + ((it) << 7)) + lane * 16;           \
        __builtin_amdgcn_global_load_lds(                                         \
            (const __attribute__((address_space(1))) void*)_gB,                   \
            (__attribute__((address_space(3))) void*)((slotp) + 1024), 16, 0, 0); \
    }                                                                             \
} while (0)

// compute both edges of the pair from already-read slot regs
#define PAIR_COMPUTE(it, ji2, mm2, dd2) do {                                      \
    const unsigned int wi_ = tab[(rw + ((it) << 7) + (lane << 1)) >> kshift];     \
    const unsigned int wj0 = tab[ji2.x];                                          \
    const unsigned int wj1 = tab[ji2.y];                                          \
    const float zpi = fmaf((float)(wi_ >> 7), qs, qb);                            \
    const float Zi  = (float)(wi_ & 0x7Fu);                                       \
    const float zpj0 = fmaf((float)(wj0 >> 7), qs, qb);                           \
    const float Zj0  = (float)(wj0 & 0x7Fu);                                      \
    const float zpj1 = fmaf((float)(wj1 >> 7), qs, qb);                           \
    const float Zj1  = (float)(wj1 & 0x7Fu);                                      \
    const float zz0 = Zi * Zj0 * mm2.x;                                           \
    const float zz1 = Zi * Zj1 * mm2.y;                                           \
    const float ad0 = (zpi + zpj0) * (mm2.x * dd2.x);                             \
    const float ad1 = (zpi + zpj1) * (mm2.y * dd2.y);                             \
    const float f0 = exp2f(fmaf(e1, ad0, l1)) + exp2f(fmaf(e2, ad0, l2))          \
                   + exp2f(fmaf(e3, ad0, l3)) + exp2f(fmaf(e4, ad0, l4));         \
    const float f1 = exp2f(fmaf(e1, ad1, l1)) + exp2f(fmaf(e2, ad1, l2))          \
                   + exp2f(fmaf(e3, ad1, l3)) + exp2f(fmaf(e4, ad1, l4));         \
    acc += f0 * zz0 * __builtin_amdgcn_rcpf(dd2.x);                               \
    acc += f1 * zz1 * __builtin_amdgcn_rcpf(dd2.y);                               \
} while (0)

#define READ_SLOT(sp, ji2, mm2, dd2) do {                                         \
    ji2 = *(const int2*)  ((sp) + (lane << 3));                                   \
    mm2 = *(const float2*)((sp) + 512 + (lane << 3));                             \
    dd2 = *(const float2*)((sp) + 1024 + (lane << 3));                            \
} while (0)

__global__ __launch_bounds__(512, 8) void zbl_main11(
        const int*            __restrict__ neighbors,
        const float*          __restrict__ mask,
        const float*          __restrict__ dist,
        const unsigned short* __restrict__ packed,
        const float*          __restrict__ scal,
        float*                __restrict__ out,
        int N, int kshift, int epb)
{
    __shared__ char stage[WPB][DEPTH][SLOTB];   // 24576 B static

    const int tid  = threadIdx.x;
    const int w    = tid >> 6;
    const int lane = tid & 63;
    const int b    = blockIdx.y;

    // wave's contiguous edge span within batch b
    const int rw = (blockIdx.x * WPB + w) * (ITERS * GRAN);
    const size_t ebase = (size_t)b * epb + (size_t)rw;
    const int*   nb_ = neighbors + ebase;
    const float* mk_ = mask      + ebase;
    const float* ds_ = dist      + ebase;

    // 1) tab global loads first (oldest in vmem queue)
    const uint4* s4 = (const uint4*)(packed + (size_t)b * N);
    const int n8 = N >> 3;                      // # of uint4 (<= 1024)
    uint4 tv0, tv1;
    const bool h0 = (tid < n8);
    const bool h1 = (tid + 512 < n8);
    if (h0) tv0 = s4[tid];
    if (h1) tv1 = s4[tid + 512];

    // 2) ring prologue: issue DEPTH slots (2 instrs each)
    {
        char* sp0 = &stage[w][0][0]; STAGE2(sp0, 0);
        char* sp1 = &stage[w][1][0]; STAGE2(sp1, 1);
    }

    // 3) write tab to LDS, then barrier
    {
        uint4* t4 = (uint4*)tab;
        if (h0) t4[tid] = tv0;
        if (h1) t4[tid + 512] = tv1;
    }
    const float e1 = scal[5],  e2 = scal[6],  e3 = scal[7],  e4 = scal[8];
    const float qb = scal[9],  qs = scal[10];
    const float l1 = scal[11], l2 = scal[12], l3 = scal[13], l4 = scal[14];
    __syncthreads();

    float acc = 0.f;
    int it = 0;

    // main loop: steady-state counted wait, restage same slot, no barriers
    for (; it < ITERS - DEPTH; ++it) {
        asm volatile("s_waitcnt vmcnt(2)" ::: "memory");     // slot 'it' landed
        char* sp = &stage[w][it & (DEPTH - 1)][0];
        int2 ji2; float2 mm2, dd2;
        READ_SLOT(sp, ji2, mm2, dd2);
        asm volatile("s_waitcnt lgkmcnt(0)" ::: "memory");   // slot consumed
        STAGE2(sp, it + DEPTH);                              // safe WAW reuse
        PAIR_COMPUTE(it, ji2, mm2, dd2);
    }

    // epilogue: 2 iterations with tightening waits (2/0), no restage
    {
        asm volatile("s_waitcnt vmcnt(2)" ::: "memory");
        char* sp = &stage[w][it & (DEPTH - 1)][0];
        int2 ji2; float2 mm2, dd2;
        READ_SLOT(sp, ji2, mm2, dd2);
        PAIR_COMPUTE(it, ji2, mm2, dd2);
        ++it;
    }
    {
        asm volatile("s_waitcnt vmcnt(0)" ::: "memory");
        char* sp = &stage[w][it & (DEPTH - 1)][0];
        int2 ji2; float2 mm2, dd2;
        READ_SLOT(sp, ji2, mm2, dd2);
        PAIR_COMPUTE(it, ji2, mm2, dd2);
        ++it;
    }

    // reduce: wave shuffle, then cross-wave via reused stage LDS, one atomic
    #pragma unroll
    for (int off = 32; off > 0; off >>= 1) acc += __shfl_down(acc, off);
    __syncthreads();                        // all waves past vmcnt(0)
    float* wred = (float*)&stage[0][0][0];  // reuse (all ring traffic done)
    if (lane == 0) wred[w] = acc;
    __syncthreads();
    if (tid == 0) {
        float t = 0.f;
        #pragma unroll
        for (int i = 0; i < WPB; ++i) t += wred[i];
        atomicAdd(&out[b], t);
    }
}

// ---------------- fallback (generic shapes, not used in bench) ----------------
__global__ void zbl_fallback(const int* __restrict__ neighbors,
                             const float* __restrict__ mask,
                             const float* __restrict__ dist,
                             const unsigned short* __restrict__ packed,
                             const float* __restrict__ scal,
                             float* __restrict__ out,
                             int N, int K, int epb, int total_edges)
{
    const int e = blockIdx.x * blockDim.x + threadIdx.x;
    if (e >= total_edges) return;
    const float e1 = scal[5], e2 = scal[6], e3 = scal[7], e4 = scal[8];
    const float qb = scal[9], qs = scal[10];
    const float l1 = scal[11], l2 = scal[12], l3 = scal[13], l4 = scal[14];
    const int b = e / epb;
    const int n = (e - b * epb) / K;
    const unsigned int wi = packed[(size_t)b * N + n];
    const unsigned int wj = packed[(size_t)b * N + neighbors[e]];
    const float zpi = fmaf((float)(wi >> 7), qs, qb);
    const float zpj = fmaf((float)(wj >> 7), qs, qb);
    const float Zi = (float)(wi & 0x7Fu), Zj = (float)(wj & 0x7Fu);
    const float m = mask[e], d = dist[e];
    const float ad = (zpi + zpj) * (m * d);
    const float f = exp2f(fmaf(e1, ad, l1)) + exp2f(fmaf(e2, ad, l2))
                  + exp2f(fmaf(e3, ad, l3)) + exp2f(fmaf(e4, ad, l4));
    const float corr = (m != 0.f) ? (f * Zi * Zj * m / d) : 0.f;
    if (corr != 0.f) atomicAdd(&out[b], corr);
}

extern "C" void kernel_launch(void* const* d_in, const int* in_sizes, int n_in,
                              void* d_out, int out_size, void* d_ws, size_t ws_size,
                              hipStream_t stream) {
    const int*   neighbors = (const int*)  d_in[0];
    const float* nb_mask   = (const float*)d_in[1];
    const int*   zn        = (const int*)  d_in[2];
    const float* dist      = (const float*)d_in[3];
    const float* adiv = (const float*)d_in[4];
    const float* apow = (const float*)d_in[5];
    const float* c1 = (const float*)d_in[6];
    const float* c2 = (const float*)d_in[7];
    const float* c3 = (const float*)d_in[8];
    const float* c4 = (const float*)d_in[9];
    const float* a1 = (const float*)d_in[10];
    const float* a2 = (const float*)d_in[11];
    const float* a3 = (const float*)d_in[12];
    const float* a4 = (const float*)d_in[13];

    const int total_edges = in_sizes[0];   // B*N*K
    const int total_atoms = in_sizes[2];   // B*N
    const int B = out_size;                // [B,1] fp32 output
    const int N = total_atoms / B;
    const int K = total_edges / total_atoms;
    const int epb = N * K;

    float*          scal   = (float*)d_ws;                         // 15 f32
    unsigned short* packed = (unsigned short*)((char*)d_ws + 64);  // B*N u16

    hipMemsetAsync(d_out, 0, (size_t)out_size * sizeof(float), stream);

    {
        const int threads = 256;
        const int blocks = (total_atoms + threads - 1) / threads;
        zbl_pre<<<blocks, threads, 0, stream>>>(zn, adiv, apow, c1, c2, c3, c4,
                                                a1, a2, a3, a4,
                                                packed, scal, total_atoms);
    }

    int kshift = 0;
    while ((1 << kshift) < K && kshift < 30) kshift++;
    const bool kpow2 = ((1 << kshift) == K);

    const int span_block = WPB * GRAN * ITERS;          // 16384 edges/block
    const bool fast = kpow2 && (kshift >= 1) && (N % 8 == 0) && (N <= 8192) &&
                      (epb % span_block == 0) &&
                      ((size_t)(64 + (size_t)total_atoms * 2) <= ws_size);
    if (fast) {
        const int bpb = epb / span_block;               // blocks per batch
        dim3 grid(bpb, B);
        zbl_main11<<<grid, 512, (size_t)N * 2, stream>>>(
            neighbors, nb_mask, dist, packed, scal, (float*)d_out,
            N, kshift, epb);
    } else {
        const int threads = 256;
        const int blocks = (total_edges + threads - 1) / threads;
        zbl_fallback<<<blocks, threads, 0, stream>>>(
            neighbors, nb_mask, dist, packed, scal, (float*)d_out,
            N, K, epb, total_edges);
    }
}

// Round 12
// 53.159 us; speedup vs baseline: 1.1662x; 1.0550x over previous
//
#include <hip/hip_runtime.h>

// ZBL repulsion energy: out[b] = sum_{n,k} KEHALF * f(a*d) * Zi*Zj*mask / d
// B=16, N=8192, K=128 in the bench (shapes derived from in_sizes).
//
// Round-12 = R8 (best: 51.75us) with the per-iteration lgkmcnt(0) removed:
//  - restage the buffer consumed in the PREVIOUS iteration (its ds_reads are
//    provably drained by last iter's VALU use) -> no explicit lgkmcnt in the
//    loop; DMA issue moves to the top of the iteration.
//  - row atom tab[(rw+it*64)>>kshift] is lane-uniform for K>=64 -> broadcast
//    read + uniform decode hoisted (one less gather+decode per iteration).
//  - steady s_waitcnt vmcnt(2); epilogue 2/2/1/0. LDS 40960B -> 4 blocks/CU,
//    32 waves/CU. Same grid (64,16), 512 threads.

#define KEHALF_F 7.199822675975274f
#define LOG2E_F  1.4426950408889634f
#define DEPTH    4
#define GRAN     64       // edges per wave-iteration
#define WPB      8        // waves per block (512 threads)
#define SLOTB    768      // 256B idx + 256B mask + 256B dist
#define ITERS    32

__device__ __forceinline__ float softplus_f(float x) {
    return (x > 20.f) ? x : log1pf(__expf(x));
}

// ---------------- precompute: scalars + packed u16 per-atom table ----------------
// scal: [5..8]=e_i(=-sp(a_i)*log2e) [9]=qb [10]=qs [11..14]=log2(w_i*KEHALF)
__global__ void zbl_pre(const int* __restrict__ zn,
                        const float* __restrict__ adiv,
                        const float* __restrict__ apow,
                        const float* __restrict__ c1, const float* __restrict__ c2,
                        const float* __restrict__ c3, const float* __restrict__ c4,
                        const float* __restrict__ a1, const float* __restrict__ a2,
                        const float* __restrict__ a3, const float* __restrict__ a4,
                        unsigned short* __restrict__ packed, float* __restrict__ scal,
                        int total_atoms)
{
    int i = blockIdx.x * blockDim.x + threadIdx.x;
    const float spa = softplus_f(apow[0]);
    const float sad = softplus_f(adiv[0]);
    const float qb  = sad;                                  // Z=1 -> zps=sad
    const float qmax = sad * __expf(spa * __logf(94.f));
    const float qs  = (qmax - qb) * (1.f / 511.f);
    if (i == 0) {
        float s1 = softplus_f(c1[0]), s2 = softplus_f(c2[0]);
        float s3 = softplus_f(c3[0]), s4 = softplus_f(c4[0]);
        float inv = KEHALF_F / (s1 + s2 + s3 + s4);         // fold KEHALF
        float w1 = s1 * inv, w2 = s2 * inv, w3 = s3 * inv, w4 = s4 * inv;
        scal[0] = sad;
        scal[1] = w1; scal[2] = w2; scal[3] = w3; scal[4] = w4;
        scal[5] = -softplus_f(a1[0]) * LOG2E_F;             // exp2 exponents
        scal[6] = -softplus_f(a2[0]) * LOG2E_F;
        scal[7] = -softplus_f(a3[0]) * LOG2E_F;
        scal[8] = -softplus_f(a4[0]) * LOG2E_F;
        scal[9]  = qb;
        scal[10] = qs;
        scal[11] = __log2f(w1);                             // weight -> exponent
        scal[12] = __log2f(w2);
        scal[13] = __log2f(w3);
        scal[14] = __log2f(w4);
    }
    if (i < total_atoms) {
        unsigned int Z = (unsigned int)zn[i];
        float Zf = (float)Z;
        float zps = sad * __expf(spa * __logf(Zf));         // sp(adiv) * Z^sp(apow)
        float qf = (zps - qb) / qs;
        int q = (int)(qf + 0.5f);
        if (q < 0) q = 0;
        if (q > 511) q = 511;
        packed[i] = (unsigned short)(((unsigned)q << 7) | (Z & 0x7Fu));
    }
}

// ---------------- main: depth-4 ring, restage-previous, 32 waves/CU ----------------
extern __shared__ unsigned short tab[];   // N u16 (dynamic, after static)

// one width-16 global_load_lds stages the whole 768B slot:
// lanes 0-15 -> idx bytes [0,256), 16-31 -> mask [256,512), 32-47 -> dist [512,768)
#define STAGE1(slotp, it) do {                                                    \
    const char* _g = (lane < 16) ? (const char*)(nb_ + ((it) << 6))               \
                   : (lane < 32) ? (const char*)(mk_ + ((it) << 6))               \
                                 : (const char*)(ds_ + ((it) << 6));              \
    _g += (lane & 15) * 16;                                                       \
    if (lane < 48)                                                                \
        __builtin_amdgcn_global_load_lds(                                         \
            (const __attribute__((address_space(1))) void*)_g,                    \
            (__attribute__((address_space(3))) void*)(slotp), 16, 0, 0);          \
} while (0)

// one iteration's reads + compute. wi row is lane-uniform (K >= 64).
#define BODY(it) do {                                                             \
    char* sp = &stage[w][(it) & (DEPTH - 1)][0];                                  \
    const int   ji = *(const int*)  (sp + (lane << 2));                           \
    const float mm = *(const float*)(sp + 256 + (lane << 2));                     \
    const float dd = *(const float*)(sp + 512 + (lane << 2));                     \
    const unsigned int wj_ = tab[ji];                                             \
    const unsigned int wi_ = tab[(unsigned)(rw + ((it) << 6)) >> kshift];         \
    const float zpi = fmaf((float)(wi_ >> 7), qs, qb);                            \
    const float Zi  = (float)(wi_ & 0x7Fu);                                       \
    const float zpj = fmaf((float)(wj_ >> 7), qs, qb);                            \
    const float Zj  = (float)(wj_ & 0x7Fu);                                       \
    const float zz = Zi * Zj * mm;                                                \
    const float ad = (zpi + zpj) * (mm * dd);                                     \
    const float f = exp2f(fmaf(e1, ad, l1)) + exp2f(fmaf(e2, ad, l2))             \
                  + exp2f(fmaf(e3, ad, l3)) + exp2f(fmaf(e4, ad, l4));            \
    acc += f * zz * __builtin_amdgcn_rcpf(dd);                                    \
} while (0)

__global__ __launch_bounds__(512, 8) void zbl_main12(
        const int*            __restrict__ neighbors,
        const float*          __restrict__ mask,
        const float*          __restrict__ dist,
        const unsigned short* __restrict__ packed,
        const float*          __restrict__ scal,
        float*                __restrict__ out,
        int N, int kshift, int epb)
{
    __shared__ char stage[WPB][DEPTH][SLOTB];   // 24576 B static

    const int tid  = threadIdx.x;
    const int w    = tid >> 6;
    const int lane = tid & 63;
    const int b    = blockIdx.y;

    // wave's contiguous edge span within batch b
    const int rw = (blockIdx.x * WPB + w) * (ITERS * GRAN);
    const size_t ebase = (size_t)b * epb + (size_t)rw;
    const int*   nb_ = neighbors + ebase;
    const float* mk_ = mask      + ebase;
    const float* ds_ = dist      + ebase;

    // 1) tab global loads first (oldest in vmem queue)
    const uint4* s4 = (const uint4*)(packed + (size_t)b * N);
    const int n8 = N >> 3;                      // # of uint4 (<= 1024)
    uint4 tv0, tv1;
    const bool h0 = (tid < n8);
    const bool h1 = (tid + 512 < n8);
    if (h0) tv0 = s4[tid];
    if (h1) tv1 = s4[tid + 512];

    // 2) ring prologue: issue DEPTH slots (1 instr each)
    {
        char* sp0 = &stage[w][0][0]; STAGE1(sp0, 0);
        char* sp1 = &stage[w][1][0]; STAGE1(sp1, 1);
        char* sp2 = &stage[w][2][0]; STAGE1(sp2, 2);
        char* sp3 = &stage[w][3][0]; STAGE1(sp3, 3);
    }

    // 3) write tab to LDS, then barrier
    {
        uint4* t4 = (uint4*)tab;
        if (h0) t4[tid] = tv0;
        if (h1) t4[tid + 512] = tv1;
    }
    const float e1 = scal[5],  e2 = scal[6],  e3 = scal[7],  e4 = scal[8];
    const float qb = scal[9],  qs = scal[10];
    const float l1 = scal[11], l2 = scal[12], l3 = scal[13], l4 = scal[14];
    __syncthreads();

    float acc = 0.f;

    // it = 0 (peeled: nothing to restage yet)
    asm volatile("s_waitcnt vmcnt(3)" ::: "memory");
    BODY(0);

    // main loop it = 1..ITERS-DEPTH: restage PREVIOUS iter's buffer for
    // slot it+DEPTH-1 (its reads were drained by last iter's VALU use),
    // then read+compute this slot. No lgkmcnt in the loop.
    #pragma unroll 4
    for (int it = 1; it <= ITERS - DEPTH; ++it) {
        asm volatile("s_waitcnt vmcnt(2)" ::: "memory");     // slot 'it' landed
        char* spre = &stage[w][(it - 1) & (DEPTH - 1)][0];
        STAGE1(spre, it + DEPTH - 1);
        BODY(it);
    }

    // epilogue: it = 29,30,31 (no restage), tightening counts
    asm volatile("s_waitcnt vmcnt(2)" ::: "memory");
    BODY(ITERS - 3);
    asm volatile("s_waitcnt vmcnt(1)" ::: "memory");
    BODY(ITERS - 2);
    asm volatile("s_waitcnt vmcnt(0)" ::: "memory");
    BODY(ITERS - 1);

    // reduce: wave shuffle, then cross-wave via reused stage LDS, one atomic
    #pragma unroll
    for (int off = 32; off > 0; off >>= 1) acc += __shfl_down(acc, off);
    __syncthreads();                        // all waves done (vmcnt drained)
    float* wred = (float*)&stage[0][0][0];  // reuse (all ring traffic done)
    if (lane == 0) wred[w] = acc;
    __syncthreads();
    if (tid == 0) {
        float t = 0.f;
        #pragma unroll
        for (int i = 0; i < WPB; ++i) t += wred[i];
        atomicAdd(&out[b], t);
    }
}

// ---------------- fallback (generic shapes, not used in bench) ----------------
__global__ void zbl_fallback(const int* __restrict__ neighbors,
                             const float* __restrict__ mask,
                             const float* __restrict__ dist,
                             const unsigned short* __restrict__ packed,
                             const float* __restrict__ scal,
                             float* __restrict__ out,
                             int N, int K, int epb, int total_edges)
{
    const int e = blockIdx.x * blockDim.x + threadIdx.x;
    if (e >= total_edges) return;
    const float e1 = scal[5], e2 = scal[6], e3 = scal[7], e4 = scal[8];
    const float qb = scal[9], qs = scal[10];
    const float l1 = scal[11], l2 = scal[12], l3 = scal[13], l4 = scal[14];
    const int b = e / epb;
    const int n = (e - b * epb) / K;
    const unsigned int wi = packed[(size_t)b * N + n];
    const unsigned int wj = packed[(size_t)b * N + neighbors[e]];
    const float zpi = fmaf((float)(wi >> 7), qs, qb);
    const float zpj = fmaf((float)(wj >> 7), qs, qb);
    const float Zi = (float)(wi & 0x7Fu), Zj = (float)(wj & 0x7Fu);
    const float m = mask[e], d = dist[e];
    const float ad = (zpi + zpj) * (m * d);
    const float f = exp2f(fmaf(e1, ad, l1)) + exp2f(fmaf(e2, ad, l2))
                  + exp2f(fmaf(e3, ad, l3)) + exp2f(fmaf(e4, ad, l4));
    const float corr = (m != 0.f) ? (f * Zi * Zj * m / d) : 0.f;
    if (corr != 0.f) atomicAdd(&out[b], corr);
}

extern "C" void kernel_launch(void* const* d_in, const int* in_sizes, int n_in,
                              void* d_out, int out_size, void* d_ws, size_t ws_size,
                              hipStream_t stream) {
    const int*   neighbors = (const int*)  d_in[0];
    const float* nb_mask   = (const float*)d_in[1];
    const int*   zn        = (const int*)  d_in[2];
    const float* dist      = (const float*)d_in[3];
    const float* adiv = (const float*)d_in[4];
    const float* apow = (const float*)d_in[5];
    const float* c1 = (const float*)d_in[6];
    const float* c2 = (const float*)d_in[7];
    const float* c3 = (const float*)d_in[8];
    const float* c4 = (const float*)d_in[9];
    const float* a1 = (const float*)d_in[10];
    const float* a2 = (const float*)d_in[11];
    const float* a3 = (const float*)d_in[12];
    const float* a4 = (const float*)d_in[13];

    const int total_edges = in_sizes[0];   // B*N*K
    const int total_atoms = in_sizes[2];   // B*N
    const int B = out_size;                // [B,1] fp32 output
    const int N = total_atoms / B;
    const int K = total_edges / total_atoms;
    const int epb = N * K;

    float*          scal   = (float*)d_ws;                         // 15 f32
    unsigned short* packed = (unsigned short*)((char*)d_ws + 64);  // B*N u16

    hipMemsetAsync(d_out, 0, (size_t)out_size * sizeof(float), stream);

    {
        const int threads = 256;
        const int blocks = (total_atoms + threads - 1) / threads;
        zbl_pre<<<blocks, threads, 0, stream>>>(zn, adiv, apow, c1, c2, c3, c4,
                                                a1, a2, a3, a4,
                                                packed, scal, total_atoms);
    }

    int kshift = 0;
    while ((1 << kshift) < K && kshift < 30) kshift++;
    const bool kpow2 = ((1 << kshift) == K);

    const int span_block = WPB * GRAN * ITERS;          // 16384 edges/block
    const bool fast = kpow2 && (kshift >= 6) && (N % 8 == 0) && (N <= 8192) &&
                      (epb % span_block == 0) &&
                      ((size_t)(64 + (size_t)total_atoms * 2) <= ws_size);
    if (fast) {
        const int bpb = epb / span_block;               // blocks per batch
        dim3 grid(bpb, B);
        zbl_main12<<<grid, 512, (size_t)N * 2, stream>>>(
            neighbors, nb_mask, dist, packed, scal, (float*)d_out,
            N, kshift, epb);
    } else {
        const int threads = 256;
        const int blocks = (total_edges + threads - 1) / threads;
        zbl_fallback<<<blocks, threads, 0, stream>>>(
            neighbors, nb_mask, dist, packed, scal, (float*)d_out,
            N, K, epb, total_edges);
    }
}